// Round 24
// baseline (226.309 us; speedup 1.0000x reference)
//
#include <hip/hip_runtime.h>
#include <hip/hip_bf16.h>
#include <math.h>

#define NB 4
#define NC 256
#define NCI 128
#define NC2 512
#define NPOS 4096
#define ISPLIT 16

using bf16x8 = __attribute__((ext_vector_type(8))) short;
using f32x4  = __attribute__((ext_vector_type(4))) float;
using f32x16 = __attribute__((ext_vector_type(16))) float;

__device__ inline unsigned short f2bf(float f) {
  unsigned int u = __float_as_uint(f);
  u = (u + 0x7fffu + ((u >> 16) & 1u)) >> 16;
  return (unsigned short)u;
}
__device__ inline float bf2f(short s) {
  return __uint_as_float(((unsigned int)(unsigned short)s) << 16);
}
__device__ inline unsigned int pk2bf(float a, float b) {
  float2 f2; f2.x = a; f2.y = b;
  __hip_bfloat162 hb = __float22bfloat162_rn(f2);
  return *reinterpret_cast<unsigned int*>(&hb);
}

// ------- fused transpose-cast for x, x_dsm, x0  (+ y==16: weight cast) -------
__global__ __launch_bounds__(256) void k_tcast_all(
    const float* __restrict__ x, const float* __restrict__ xdsm,
    const float* __restrict__ x0, short* __restrict__ xT,
    short* __restrict__ xdT, short* __restrict__ x0T,
    const float* __restrict__ wsrc0, short* __restrict__ wdst0,   // 32768
    const float* __restrict__ wsrc1, short* __restrict__ wdst1,   // 32768
    const float* __restrict__ wsrc2, short* __restrict__ wdst2,   // 131072
    const float* __restrict__ wsrc3, short* __restrict__ wdst3) { // 131072
  __shared__ float t[64][65];
  const int tid = threadIdx.x;
  const int y = blockIdx.y, c0 = blockIdx.x * 64, b = blockIdx.z;
  if (y == 16) {
    int g = ((b * 64 + blockIdx.x) * 256 + tid) * 5;
#pragma unroll
    for (int k = 0; k < 5; ++k) {
      int i = g + k;
      if (i < 32768) { wdst0[i] = (short)f2bf(wsrc0[i]); continue; }
      i -= 32768;
      if (i < 32768) { wdst1[i] = (short)f2bf(wsrc1[i]); continue; }
      i -= 32768;
      if (i < 131072) { wdst2[i] = (short)f2bf(wsrc2[i]); continue; }
      i -= 131072;
      wdst3[i] = (short)f2bf(wsrc3[i]);
    }
    return;
  }
  const float* in; short* out; int R, r0;
  if (y < 4)      { in = x;    out = xT;  R = NC;  r0 = y * 64; }
  else if (y < 8) { in = xdsm; out = xdT; R = NC;  r0 = (y - 4) * 64; }
  else            { in = x0;   out = x0T; R = NC2; r0 = (y - 8) * 64; }
  const size_t inBs = (size_t)R * NPOS, outBs = (size_t)NPOS * R;
  {
    int r = tid >> 2, cc = (tid & 3) * 16;
    const float* ib = in + (size_t)b * inBs + (size_t)(r0 + r) * NPOS + c0 + cc;
#pragma unroll
    for (int i = 0; i < 4; ++i) {
      float4 v = *(const float4*)(ib + i * 4);
      t[r][cc + i * 4 + 0] = v.x; t[r][cc + i * 4 + 1] = v.y;
      t[r][cc + i * 4 + 2] = v.z; t[r][cc + i * 4 + 3] = v.w;
    }
  }
  __syncthreads();
  {
    int c = tid >> 2, rr = (tid & 3) * 16;
    __align__(16) short v[16];
#pragma unroll
    for (int i = 0; i < 16; ++i) v[i] = (short)f2bf(t[rr + i][c]);
    short* ob = out + (size_t)b * outBs + (size_t)(c0 + c) * R + r0 + rr;
    *(int4*)(ob) = *(const int4*)(v);
    *(int4*)(ob + 8) = *(const int4*)(v + 8);
  }
}

// ---------------- sum 4 bf16 partials [p][b][cc][i] -> transpose [b][i][cc] bf16
__global__ __launch_bounds__(256) void k_tcast4(
    const short* __restrict__ inP, short* __restrict__ out) {
  __shared__ float t[64][65];
  const int tid = threadIdx.x;
  const int r0 = blockIdx.y * 64, c0 = blockIdx.x * 64, b = blockIdx.z;
  {
    int r = tid >> 2, cc = (tid & 3) * 16;
    float tacc[16] = {};
#pragma unroll
    for (int p = 0; p < 4; ++p) {
      const short* ib = inP + ((size_t)p * NB + b) * NC * NPOS +
                        (size_t)(r0 + r) * NPOS + c0 + cc;
      bf16x8 a = *(const bf16x8*)(ib);
      bf16x8 a2 = *(const bf16x8*)(ib + 8);
#pragma unroll
      for (int i = 0; i < 8; ++i) { tacc[i] += bf2f(a[i]); tacc[8 + i] += bf2f(a2[i]); }
    }
#pragma unroll
    for (int i = 0; i < 16; ++i) t[r][cc + i] = tacc[i];
  }
  __syncthreads();
  {
    int c = tid >> 2, rr = (tid & 3) * 16;
    __align__(16) short v[16];
#pragma unroll
    for (int i = 0; i < 16; ++i) v[i] = (short)f2bf(t[rr + i][c]);
    short* ob = out + (size_t)b * (size_t)NPOS * NC + (size_t)(c0 + c) * NC + r0 + rr;
    *(int4*)(ob) = *(const int4*)(v);
    *(int4*)(ob + 8) = *(const int4*)(v + 8);
  }
}

// ---------------- generic bf16 MFMA GEMM ----------------
// SCALE_M: multiply output by 1/sum_t plsum[b][t][m]. DUAL: z>=NB -> (A2,B2,out2).
template<bool OUT_BF16, bool HAS_RES, bool SCALE_M, bool DUAL>
__global__ __launch_bounds__(256, 4) void k_gemm(
    const short* __restrict__ A, const short* __restrict__ B,
    void* __restrict__ outv, const float* __restrict__ res,
    const float* __restrict__ plsumP,
    const short* __restrict__ A2, const short* __restrict__ B2,
    void* __restrict__ outv2,
    int K, int sN, size_t aBs, size_t bBs, size_t oBs) {
  __shared__ short As[2][64 * 64];
  __shared__ short Bs_[2][64 * 64];
  const int tid = threadIdx.x, lane = tid & 63, w = tid >> 6;
  const int x = lane & 15, q = lane >> 4;
  const int wm = (w & 1) * 32, wn = (w >> 1) * 32;
  int b = blockIdx.z;
  if (DUAL && b >= NB) {
    A = A2; B = B2; outv = outv2; b -= NB;
  }
  const int n0 = blockIdx.x * 64, m0 = blockIdx.y * 64;
  const short* Ab = A + (size_t)b * aBs + (size_t)m0 * K;
  const short* Bb = B + (size_t)b * bBs + (size_t)n0 * K;
  const int r = tid >> 2, cth = tid & 3;
  f32x4 acc[2][2];
  acc[0][0] = acc[0][1] = acc[1][0] = acc[1][1] = (f32x4){0.f, 0.f, 0.f, 0.f};
  int4 ra[2], rb[2];
  const int NK = K >> 6;
#define GLOAD(kt)                                                              \
  { _Pragma("unroll") for (int i = 0; i < 2; ++i) {                            \
      ra[i] = *(const int4*)(Ab + (size_t)r * K + (kt) * 64 + (cth + i * 4) * 8); \
      rb[i] = *(const int4*)(Bb + (size_t)r * K + (kt) * 64 + (cth + i * 4) * 8); } }
#define GWRITE(buf)                                                            \
  { _Pragma("unroll") for (int i = 0; i < 2; ++i) {                            \
      *(int4*)(&As[buf][r * 64 + (((cth + i * 4) ^ (r & 7)) * 8)]) = ra[i];    \
      *(int4*)(&Bs_[buf][r * 64 + (((cth + i * 4) ^ (r & 7)) * 8)]) = rb[i]; } }
  GLOAD(0); GWRITE(0); __syncthreads();
  int cur = 0;
  for (int kt = 0; kt < NK; ++kt) {
    if (kt + 1 < NK) GLOAD(kt + 1);
    bf16x8 af[2][2], bfr[2][2];
#pragma unroll
    for (int ms = 0; ms < 2; ++ms) {
      int rowm = wm + ms * 16 + x;
#pragma unroll
      for (int ks = 0; ks < 2; ++ks)
        af[ms][ks] = *(const bf16x8*)(&As[cur][rowm * 64 + (((ks * 4 + q) ^ (rowm & 7)) * 8)]);
    }
#pragma unroll
    for (int ns = 0; ns < 2; ++ns) {
      int rown = wn + ns * 16 + x;
#pragma unroll
      for (int ks = 0; ks < 2; ++ks)
        bfr[ns][ks] = *(const bf16x8*)(&Bs_[cur][rown * 64 + (((ks * 4 + q) ^ (rown & 7)) * 8)]);
    }
#pragma unroll
    for (int ms = 0; ms < 2; ++ms)
#pragma unroll
      for (int ns = 0; ns < 2; ++ns)
#pragma unroll
        for (int ks = 0; ks < 2; ++ks)
          acc[ms][ns] = __builtin_amdgcn_mfma_f32_16x16x32_bf16(
              af[ms][ks], bfr[ns][ks], acc[ms][ns], 0, 0, 0);
    if (kt + 1 < NK) GWRITE(cur ^ 1);
    __syncthreads();
    cur ^= 1;
  }
  float4 sv[2] = {{1.f, 1.f, 1.f, 1.f}, {1.f, 1.f, 1.f, 1.f}};
  if (SCALE_M) {
#pragma unroll
    for (int ms = 0; ms < 2; ++ms) {
      int m = m0 + wm + ms * 16 + q * 4;
      float4 s = {0.f, 0.f, 0.f, 0.f};
#pragma unroll
      for (int t = 0; t < ISPLIT; ++t) {
        float4 pv = *(const float4*)(plsumP + ((size_t)(b * ISPLIT + t) << 12) + m);
        s.x += pv.x; s.y += pv.y; s.z += pv.z; s.w += pv.w;
      }
      sv[ms].x = 1.0f / s.x; sv[ms].y = 1.0f / s.y;
      sv[ms].z = 1.0f / s.z; sv[ms].w = 1.0f / s.w;
    }
  }
#pragma unroll
  for (int ms = 0; ms < 2; ++ms)
#pragma unroll
    for (int ns = 0; ns < 2; ++ns) {
      int n = n0 + wn + ns * 16 + x;
      int m = m0 + wm + ms * 16 + q * 4;
      size_t off = (size_t)b * oBs + (size_t)n * sN + m;
      if (OUT_BF16) {
        __align__(8) short pv[4];
        pv[0] = (short)f2bf(acc[ms][ns][0] * sv[ms].x);
        pv[1] = (short)f2bf(acc[ms][ns][1] * sv[ms].y);
        pv[2] = (short)f2bf(acc[ms][ns][2] * sv[ms].z);
        pv[3] = (short)f2bf(acc[ms][ns][3] * sv[ms].w);
        *(uint2*)((short*)outv + off) = *(const uint2*)pv;
      } else {
        float4 v = {acc[ms][ns][0], acc[ms][ns][1], acc[ms][ns][2], acc[ms][ns][3]};
        if (HAS_RES) {
          float4 rv = *(const float4*)(res + off);
          v.x += rv.x; v.y += rv.y; v.z += rv.z; v.w += rv.w;
        }
        *(float4*)((float*)outv + off) = v;
      }
    }
#undef GLOAD
#undef GWRITE
}

// ---------------- partial l[j], 32x32 MFMA: plsum[b][iy][j] ----------------
__global__ __launch_bounds__(256, 4) void k_lsum(
    const short* __restrict__ phiB, const short* __restrict__ thetaB,
    float* __restrict__ plsum) {
  __shared__ short thT[2][32 * 128];   // 8KB each, chunk-swizzled ^(row&7)
  const int tid = threadIdx.x, lane = tid & 63, w = tid >> 6;
  const int il = lane & 31, h = lane >> 5;
  const int j0 = blockIdx.x * 128, iy = blockIdx.y, b = blockIdx.z;
  const short* phb = phiB + (size_t)b * NPOS * NCI;
  const short* thb = thetaB + (size_t)b * NPOS * NCI + (size_t)iy * (NPOS / ISPLIT) * NCI;
  bf16x8 pf[8];
  {
    const short* pr = phb + (size_t)(j0 + w * 32 + il) * NCI;
#pragma unroll
    for (int kk = 0; kk < 8; ++kk) pf[kk] = *(const bf16x8*)(pr + kk * 16 + h * 8);
  }
  float lsum = 0.f;
  int4 rt[2];
  const int NIT = NPOS / ISPLIT / 32;   // 8
#define LSUM_LOAD(it)                                                         \
  { _Pragma("unroll") for (int r = 0; r < 2; ++r) {                           \
      int s = tid + r * 256; int row = s >> 4, c = s & 15;                    \
      rt[r] = *(const int4*)(thb + (size_t)((it) * 32 + row) * NCI + c * 8); } }
#define LSUM_WRITE(buf)                                                       \
  { _Pragma("unroll") for (int r = 0; r < 2; ++r) {                           \
      int s = tid + r * 256; int row = s >> 4, c = s & 15;                    \
      *(int4*)(&thT[buf][row * 128 + ((c ^ (row & 7)) * 8)]) = rt[r]; } }
  LSUM_LOAD(0); LSUM_WRITE(0); __syncthreads();
  int cur = 0;
  const int swz = il & 7;
  for (int it = 0; it < NIT; ++it) {
    if (it + 1 < NIT) LSUM_LOAD(it + 1);
    f32x16 s16;
#pragma unroll
    for (int r = 0; r < 16; ++r) s16[r] = 0.f;
#pragma unroll
    for (int kk = 0; kk < 8; ++kk) {
      bf16x8 a = *(const bf16x8*)(&thT[cur][il * 128 + (((2 * kk + h) ^ swz) * 8)]);
      s16 = __builtin_amdgcn_mfma_f32_32x32x16_bf16(a, pf[kk], s16, 0, 0, 0);
    }
#pragma unroll
    for (int r = 0; r < 16; ++r) lsum += __expf(s16[r]);
    if (it + 1 < NIT) LSUM_WRITE(cur ^ 1);
    __syncthreads();
    cur ^= 1;
  }
  lsum += __shfl_xor(lsum, 32);
  if (h == 0)
    plsum[((size_t)(b * ISPLIT + iy) << 12) + j0 + w * 32 + il] = lsum;
#undef LSUM_LOAD
#undef LSUM_WRITE
}

// ---------------- attention, 32x32x16 MFMA (R19-verified) ----------------
__global__ __launch_bounds__(256, 2) void k_attn(
    const short* __restrict__ phiB, const short* __restrict__ thetaB,
    const short* __restrict__ gB, short* __restrict__ omidP) {
  __shared__ short phiT[2][32 * 128];   // 8KB each, chunk-swizzled ^(row&7)
  __shared__ short gT[2][256 * 32];     // 16KB each, slot-swizzled ^((row>>1)&3)
  __shared__ short pT[4][32 * 32];      // 2KB per wave, slot-swizzled
  const int tid = threadIdx.x, lane = tid & 63, w = tid >> 6;
  const int il = lane & 31, h = lane >> 5;
  const int key = (il >> 1) & 3;        // 16B-slot swizzle key (row = il)
  const int i0 = blockIdx.x * 128, jq = blockIdx.y, b = blockIdx.z;
  const short* phb = phiB + (size_t)b * NPOS * NCI;
  const short* thb = thetaB + (size_t)b * NPOS * NCI;
  const short* gb = gB + (size_t)b * NC * NPOS;
  short* om = omidP + ((size_t)(jq * NB + b)) * NC * NPOS;

  bf16x8 tf[8];
  {
    const short* tr = thb + (size_t)(i0 + w * 32 + il) * NCI;
#pragma unroll
    for (int kk = 0; kk < 8; ++kk) tf[kk] = *(const bf16x8*)(tr + kk * 16 + h * 8);
  }
  f32x16 acc[8];
#pragma unroll
  for (int i = 0; i < 8; ++i)
#pragma unroll
    for (int r = 0; r < 16; ++r) acc[i][r] = 0.f;

  int4 rphi[2], rg[4];
  const int NT = 32;                    // 32 j-tiles of 32 per quarter
  const int jbase = jq * 32;
#define ATTN_LOAD(jt)                                                          \
  { _Pragma("unroll") for (int r = 0; r < 2; ++r) {                            \
      int s = tid + r * 256; int row = s >> 4, c = s & 15;                     \
      rphi[r] = *(const int4*)(phb + (size_t)((jbase + (jt)) * 32 + row) * NCI + c * 8); } \
    _Pragma("unroll") for (int r = 0; r < 4; ++r) {                            \
      int s = tid + r * 256; int cc = s >> 2, c4 = s & 3;                      \
      rg[r] = *(const int4*)(gb + (size_t)cc * NPOS + (jbase + (jt)) * 32 + c4 * 8); } }
#define ATTN_WRITE(buf)                                                        \
  { _Pragma("unroll") for (int r = 0; r < 2; ++r) {                            \
      int s = tid + r * 256; int row = s >> 4, c = s & 15;                     \
      *(int4*)(&phiT[buf][row * 128 + ((c ^ (row & 7)) * 8)]) = rphi[r]; }     \
    _Pragma("unroll") for (int r = 0; r < 4; ++r) {                            \
      int s = tid + r * 256; int cc = s >> 2, c4 = s & 3;                      \
      *(int4*)(&gT[buf][cc * 32 + ((c4 ^ ((cc >> 1) & 3)) * 8)]) = rg[r]; } }
  ATTN_LOAD(0); ATTN_WRITE(0); __syncthreads();
  int cur = 0;
  for (int jt = 0; jt < NT; ++jt) {
    if (jt + 1 < NT) ATTN_LOAD(jt + 1);
    {
      const short* PH = &phiT[cur][0];
      short* PW = &pT[w][0];
      // ---- S^T: 32 j x 32 i, K=128 via 8 mfma 32x32x16 ----
      f32x16 s16;
#pragma unroll
      for (int r = 0; r < 16; ++r) s16[r] = 0.f;
      const int swp = il & 7;           // phi chunk swizzle (row = j = il)
#pragma unroll
      for (int kk = 0; kk < 8; ++kk) {
        bf16x8 a = *(const bf16x8*)(PH + il * 128 + (((2 * kk + h) ^ swp) * 8));
        s16 = __builtin_amdgcn_mfma_f32_32x32x16_bf16(a, tf[kk], s16, 0, 0, 0);
      }
      // lane holds S^T[j=(r&3)+8*(r>>2)+4h][i = i0+w*32+il]; P = exp(S)
#pragma unroll
      for (int g2 = 0; g2 < 4; ++g2) {
        unsigned int lo = pk2bf(__expf(s16[4 * g2 + 0]), __expf(s16[4 * g2 + 1]));
        unsigned int hi2 = pk2bf(__expf(s16[4 * g2 + 2]), __expf(s16[4 * g2 + 3]));
        *(uint2*)(PW + il * 32 + ((g2 ^ key) * 8) + 4 * h) = make_uint2(lo, hi2);
      }
      // ---- PV: wave's 32 i x all 256 cc ----
      const short* GT = &gT[cur][0];
      bf16x8 pa[2];
#pragma unroll
      for (int jh2 = 0; jh2 < 2; ++jh2)
        pa[jh2] = *(const bf16x8*)(PW + il * 32 + (((2 * jh2 + h) ^ key) * 8));
#pragma unroll
      for (int ct = 0; ct < 8; ++ct) {
#pragma unroll
        for (int jh2 = 0; jh2 < 2; ++jh2) {
          bf16x8 bg = *(const bf16x8*)(GT + (ct * 32 + il) * 32 + (((2 * jh2 + h) ^ key) * 8));
          acc[ct] = __builtin_amdgcn_mfma_f32_32x32x16_bf16(pa[jh2], bg, acc[ct], 0, 0, 0);
        }
      }
    }
    if (jt + 1 < NT) ATTN_WRITE(cur ^ 1);
    __syncthreads();
    cur ^= 1;
  }
#pragma unroll
  for (int ct = 0; ct < 8; ++ct)
#pragma unroll
    for (int g2 = 0; g2 < 4; ++g2) {
      unsigned int lo = pk2bf(acc[ct][4 * g2 + 0], acc[ct][4 * g2 + 1]);
      unsigned int hi2 = pk2bf(acc[ct][4 * g2 + 2], acc[ct][4 * g2 + 3]);
      size_t o = (size_t)(ct * 32 + il) * NPOS + i0 + w * 32 + 8 * g2 + 4 * h;
      *(uint2*)(om + o) = make_uint2(lo, hi2);
    }
#undef ATTN_LOAD
#undef ATTN_WRITE
}

extern "C" void kernel_launch(void* const* d_in, const int* in_sizes, int n_in,
                              void* d_out, int out_size, void* d_ws, size_t ws_size,
                              hipStream_t stream) {
  (void)in_sizes; (void)n_in; (void)out_size; (void)ws_size;
  const float* x0      = (const float*)d_in[0];
  const float* x       = (const float*)d_in[1];
  const float* x_dsm   = (const float*)d_in[2];
  const float* w_phi   = (const float*)d_in[3];
  const float* w_theta = (const float*)d_in[4];
  const float* w_g     = (const float*)d_in[5];
  const float* w_mask  = (const float*)d_in[6];
  float* outp = (float*)d_out;

  short* sp = (short*)d_ws;
  short* wb_phi   = sp; sp += 32768;
  short* wb_theta = sp; sp += 32768;
  short* wb_g     = sp; sp += 131072;
  short* wb_mask  = sp; sp += 131072;
  short* xT   = sp; sp += (size_t)NB * NPOS * NC;          // 8MB
  short* xdT  = sp; sp += (size_t)NB * NPOS * NC;          // 8MB
  short* x0T  = sp; sp += (size_t)NB * NPOS * NC2;         // 16MB
  short* phiB   = sp; sp += (size_t)NB * NPOS * NCI;       // 4MB
  short* thetaB = sp; sp += (size_t)NB * NPOS * NCI;       // 4MB
  short* gBuf   = sp; sp += (size_t)NB * NC * NPOS;        // 8MB
  float* plsum = (float*)sp;                               // [b][ISPLIT][NPOS] = 1MB
  short* omidP = xT;       // 4 bf16 partials x 8MB = 32MB, aliases dead xT/xdT/x0T
  short* omidT = phiB;     // 8MB bf16 [b][p][cc], aliases dead phiB/thetaB

  // transpose-casts + weight cast (y==16)
  k_tcast_all<<<dim3(64, 17, NB), 256, 0, stream>>>(
      x, x_dsm, x0, xT, xdT, x0T,
      w_phi, wb_phi, w_theta, wb_theta, w_g, wb_g, w_mask, wb_mask);

  // phi + theta in one dispatch (z<NB: phi from xT; z>=NB: theta from xdT)
  k_gemm<true, false, false, true><<<dim3(64, 2, 2 * NB), 256, 0, stream>>>(
      wb_phi, xT, phiB, nullptr, nullptr, wb_theta, xdT, thetaB,
      NC, NCI, 0, (size_t)NPOS * NC, (size_t)NPOS * NCI);

  k_lsum<<<dim3(NPOS / 128, ISPLIT, NB), 256, 0, stream>>>(phiB, thetaB, plsum);

  // g[cc][p] = (sum_c x0T[p][c] W_g[cc][c]) * (1/sum_t plsum[b][t][p])
  k_gemm<true, false, true, false><<<dim3(4, 64, NB), 256, 0, stream>>>(
      x0T, wb_g, gBuf, nullptr, plsum, nullptr, nullptr, nullptr,
      NC2, NPOS, (size_t)NPOS * NC2, 0, (size_t)NC * NPOS);

  k_attn<<<dim3(NPOS / 128, 4, NB), 256, 0, stream>>>(phiB, thetaB, gBuf, omidP);

  k_tcast4<<<dim3(64, 4, NB), 256, 0, stream>>>(omidP, omidT);

  k_gemm<false, true, false, false><<<dim3(8, 64, NB), 256, 0, stream>>>(
      omidT, wb_mask, outp, x0, nullptr, nullptr, nullptr, nullptr,
      NC, NPOS, (size_t)NPOS * NC, 0, (size_t)NC2 * NPOS);
}

// Round 25
// 222.859 us; speedup vs baseline: 1.0155x; 1.0155x over previous
//
#include <hip/hip_runtime.h>
#include <math.h>

#define NB 4
#define NC 256
#define NCI 128
#define NC2 512
#define NPOS 4096
#define ISPLIT 8

using bf16x8 = __attribute__((ext_vector_type(8))) short;
using f32x4  = __attribute__((ext_vector_type(4))) float;
using f32x16 = __attribute__((ext_vector_type(16))) float;

__device__ inline unsigned short f2bf(float f) {
  unsigned int u = __float_as_uint(f);
  u = (u + 0x7fffu + ((u >> 16) & 1u)) >> 16;
  return (unsigned short)u;
}
__device__ inline float bf2f(short s) {
  return __uint_as_float(((unsigned int)(unsigned short)s) << 16);
}

// ------- fused transpose-cast for x, x_dsm, x0  (+ y==16: weight cast) -------
__global__ __launch_bounds__(256) void k_tcast_all(
    const float* __restrict__ x, const float* __restrict__ xdsm,
    const float* __restrict__ x0, short* __restrict__ xT,
    short* __restrict__ xdT, short* __restrict__ x0T,
    const float* __restrict__ wsrc0, short* __restrict__ wdst0,   // 32768
    const float* __restrict__ wsrc1, short* __restrict__ wdst1,   // 32768
    const float* __restrict__ wsrc2, short* __restrict__ wdst2,   // 131072
    const float* __restrict__ wsrc3, short* __restrict__ wdst3) { // 131072
  __shared__ float t[64][65];
  const int tid = threadIdx.x;
  const int y = blockIdx.y, c0 = blockIdx.x * 64, b = blockIdx.z;
  if (y == 16) {
    // weight cast: 327680 elems over 64*NB blocks * 256 threads * 5 elems
    int g = ((b * 64 + blockIdx.x) * 256 + tid) * 5;
#pragma unroll
    for (int k = 0; k < 5; ++k) {
      int i = g + k;
      if (i < 32768) { wdst0[i] = (short)f2bf(wsrc0[i]); continue; }
      i -= 32768;
      if (i < 32768) { wdst1[i] = (short)f2bf(wsrc1[i]); continue; }
      i -= 32768;
      if (i < 131072) { wdst2[i] = (short)f2bf(wsrc2[i]); continue; }
      i -= 131072;
      wdst3[i] = (short)f2bf(wsrc3[i]);
    }
    return;
  }
  const float* in; short* out; int R, r0;
  if (y < 4)      { in = x;    out = xT;  R = NC;  r0 = y * 64; }
  else if (y < 8) { in = xdsm; out = xdT; R = NC;  r0 = (y - 4) * 64; }
  else            { in = x0;   out = x0T; R = NC2; r0 = (y - 8) * 64; }
  const size_t inBs = (size_t)R * NPOS, outBs = (size_t)NPOS * R;
  {
    int r = tid >> 2, cc = (tid & 3) * 16;
    const float* ib = in + (size_t)b * inBs + (size_t)(r0 + r) * NPOS + c0 + cc;
#pragma unroll
    for (int i = 0; i < 4; ++i) {
      float4 v = *(const float4*)(ib + i * 4);
      t[r][cc + i * 4 + 0] = v.x; t[r][cc + i * 4 + 1] = v.y;
      t[r][cc + i * 4 + 2] = v.z; t[r][cc + i * 4 + 3] = v.w;
    }
  }
  __syncthreads();
  {
    int c = tid >> 2, rr = (tid & 3) * 16;
    __align__(16) short v[16];
#pragma unroll
    for (int i = 0; i < 16; ++i) v[i] = (short)f2bf(t[rr + i][c]);
    short* ob = out + (size_t)b * outBs + (size_t)(c0 + c) * R + r0 + rr;
    *(int4*)(ob) = *(const int4*)(v);
    *(int4*)(ob + 8) = *(const int4*)(v + 8);
  }
}

// ---------------- sum 4 bf16 partials [p][b][cc][i] -> transpose [b][i][cc] bf16
__global__ __launch_bounds__(256) void k_tcast4(
    const short* __restrict__ inP, short* __restrict__ out) {
  __shared__ float t[64][65];
  const int tid = threadIdx.x;
  const int r0 = blockIdx.y * 64, c0 = blockIdx.x * 64, b = blockIdx.z;
  {
    int r = tid >> 2, cc = (tid & 3) * 16;
    float tacc[16] = {};
#pragma unroll
    for (int p = 0; p < 4; ++p) {
      const short* ib = inP + ((size_t)p * NB + b) * NC * NPOS +
                        (size_t)(r0 + r) * NPOS + c0 + cc;
      bf16x8 a = *(const bf16x8*)(ib);
      bf16x8 a2 = *(const bf16x8*)(ib + 8);
#pragma unroll
      for (int i = 0; i < 8; ++i) { tacc[i] += bf2f(a[i]); tacc[8 + i] += bf2f(a2[i]); }
    }
#pragma unroll
    for (int i = 0; i < 16; ++i) t[r][cc + i] = tacc[i];
  }
  __syncthreads();
  {
    int c = tid >> 2, rr = (tid & 3) * 16;
    __align__(16) short v[16];
#pragma unroll
    for (int i = 0; i < 16; ++i) v[i] = (short)f2bf(t[rr + i][c]);
    short* ob = out + (size_t)b * (size_t)NPOS * NC + (size_t)(c0 + c) * NC + r0 + rr;
    *(int4*)(ob) = *(const int4*)(v);
    *(int4*)(ob + 8) = *(const int4*)(v + 8);
  }
}

// ---------------- generic bf16 MFMA GEMM ----------------
// SCALE_M: multiply output by 1/sum_t plsum[b][t][m] (linv computed inline).
// DUAL: grid.z in [0,2*NB), z>=NB selects (A2,B2,out2).
template<bool OUT_BF16, bool HAS_RES, bool SCALE_M, bool DUAL>
__global__ __launch_bounds__(256, 4) void k_gemm(
    const short* __restrict__ A, const short* __restrict__ B,
    void* __restrict__ outv, const float* __restrict__ res,
    const float* __restrict__ plsumP,
    const short* __restrict__ A2, const short* __restrict__ B2,
    void* __restrict__ outv2,
    int K, int sN, size_t aBs, size_t bBs, size_t oBs) {
  __shared__ short As[2][64 * 64];
  __shared__ short Bs_[2][64 * 64];
  const int tid = threadIdx.x, lane = tid & 63, w = tid >> 6;
  const int x = lane & 15, q = lane >> 4;
  const int wm = (w & 1) * 32, wn = (w >> 1) * 32;
  int b = blockIdx.z;
  if (DUAL && b >= NB) {
    A = A2; B = B2; outv = outv2; b -= NB;
  }
  const int n0 = blockIdx.x * 64, m0 = blockIdx.y * 64;
  const short* Ab = A + (size_t)b * aBs + (size_t)m0 * K;
  const short* Bb = B + (size_t)b * bBs + (size_t)n0 * K;
  const int r = tid >> 2, cth = tid & 3;
  f32x4 acc[2][2];
  acc[0][0] = acc[0][1] = acc[1][0] = acc[1][1] = (f32x4){0.f, 0.f, 0.f, 0.f};
  int4 ra[2], rb[2];
  const int NK = K >> 6;
#define GLOAD(kt)                                                              \
  { _Pragma("unroll") for (int i = 0; i < 2; ++i) {                            \
      ra[i] = *(const int4*)(Ab + (size_t)r * K + (kt) * 64 + (cth + i * 4) * 8); \
      rb[i] = *(const int4*)(Bb + (size_t)r * K + (kt) * 64 + (cth + i * 4) * 8); } }
#define GWRITE(buf)                                                            \
  { _Pragma("unroll") for (int i = 0; i < 2; ++i) {                            \
      *(int4*)(&As[buf][r * 64 + (((cth + i * 4) ^ (r & 7)) * 8)]) = ra[i];    \
      *(int4*)(&Bs_[buf][r * 64 + (((cth + i * 4) ^ (r & 7)) * 8)]) = rb[i]; } }
  GLOAD(0); GWRITE(0); __syncthreads();
  int cur = 0;
  for (int kt = 0; kt < NK; ++kt) {
    if (kt + 1 < NK) GLOAD(kt + 1);
    bf16x8 af[2][2], bfr[2][2];
#pragma unroll
    for (int ms = 0; ms < 2; ++ms) {
      int rowm = wm + ms * 16 + x;
#pragma unroll
      for (int ks = 0; ks < 2; ++ks)
        af[ms][ks] = *(const bf16x8*)(&As[cur][rowm * 64 + (((ks * 4 + q) ^ (rowm & 7)) * 8)]);
    }
#pragma unroll
    for (int ns = 0; ns < 2; ++ns) {
      int rown = wn + ns * 16 + x;
#pragma unroll
      for (int ks = 0; ks < 2; ++ks)
        bfr[ns][ks] = *(const bf16x8*)(&Bs_[cur][rown * 64 + (((ks * 4 + q) ^ (rown & 7)) * 8)]);
    }
#pragma unroll
    for (int ms = 0; ms < 2; ++ms)
#pragma unroll
      for (int ns = 0; ns < 2; ++ns)
#pragma unroll
        for (int ks = 0; ks < 2; ++ks)
          acc[ms][ns] = __builtin_amdgcn_mfma_f32_16x16x32_bf16(
              af[ms][ks], bfr[ns][ks], acc[ms][ns], 0, 0, 0);
    if (kt + 1 < NK) GWRITE(cur ^ 1);
    __syncthreads();
    cur ^= 1;
  }
  float4 sv[2] = {{1.f, 1.f, 1.f, 1.f}, {1.f, 1.f, 1.f, 1.f}};
  if (SCALE_M) {
#pragma unroll
    for (int ms = 0; ms < 2; ++ms) {
      int m = m0 + wm + ms * 16 + q * 4;
      float4 s = {0.f, 0.f, 0.f, 0.f};
#pragma unroll
      for (int t = 0; t < ISPLIT; ++t) {
        float4 pv = *(const float4*)(plsumP + ((size_t)(b * ISPLIT + t) << 12) + m);
        s.x += pv.x; s.y += pv.y; s.z += pv.z; s.w += pv.w;
      }
      sv[ms].x = 1.0f / s.x; sv[ms].y = 1.0f / s.y;
      sv[ms].z = 1.0f / s.z; sv[ms].w = 1.0f / s.w;
    }
  }
#pragma unroll
  for (int ms = 0; ms < 2; ++ms)
#pragma unroll
    for (int ns = 0; ns < 2; ++ns) {
      int n = n0 + wn + ns * 16 + x;
      int m = m0 + wm + ms * 16 + q * 4;
      size_t off = (size_t)b * oBs + (size_t)n * sN + m;
      if (OUT_BF16) {
        __align__(8) short pv[4];
        pv[0] = (short)f2bf(acc[ms][ns][0] * sv[ms].x);
        pv[1] = (short)f2bf(acc[ms][ns][1] * sv[ms].y);
        pv[2] = (short)f2bf(acc[ms][ns][2] * sv[ms].z);
        pv[3] = (short)f2bf(acc[ms][ns][3] * sv[ms].w);
        *(uint2*)((short*)outv + off) = *(const uint2*)pv;
      } else {
        float4 v = {acc[ms][ns][0], acc[ms][ns][1], acc[ms][ns][2], acc[ms][ns][3]};
        if (HAS_RES) {
          float4 rv = *(const float4*)(res + off);
          v.x += rv.x; v.y += rv.y; v.z += rv.z; v.w += rv.w;
        }
        *(float4*)((float*)outv + off) = v;
      }
    }
#undef GLOAD
#undef GWRITE
}

// ---------------- partial l[j], 32x32 MFMA: plsum[b][iy][j] ----------------
__global__ __launch_bounds__(256, 4) void k_lsum(
    const short* __restrict__ phiB, const short* __restrict__ thetaB,
    float* __restrict__ plsum) {
  __shared__ short thT[2][32 * 128];   // 8KB each, chunk-swizzled ^(row&7)
  const int tid = threadIdx.x, lane = tid & 63, w = tid >> 6;
  const int il = lane & 31, h = lane >> 5;
  const int j0 = blockIdx.x * 128, iy = blockIdx.y, b = blockIdx.z;
  const short* phb = phiB + (size_t)b * NPOS * NCI;
  const short* thb = thetaB + (size_t)b * NPOS * NCI + (size_t)iy * (NPOS / ISPLIT) * NCI;
  bf16x8 pf[8];
  {
    const short* pr = phb + (size_t)(j0 + w * 32 + il) * NCI;
#pragma unroll
    for (int kk = 0; kk < 8; ++kk) pf[kk] = *(const bf16x8*)(pr + kk * 16 + h * 8);
  }
  float lsum = 0.f;
  int4 rt[2];
  const int NIT = NPOS / ISPLIT / 32;   // 16
#define LSUM_LOAD(it)                                                         \
  { _Pragma("unroll") for (int r = 0; r < 2; ++r) {                           \
      int s = tid + r * 256; int row = s >> 4, c = s & 15;                    \
      rt[r] = *(const int4*)(thb + (size_t)((it) * 32 + row) * NCI + c * 8); } }
#define LSUM_WRITE(buf)                                                       \
  { _Pragma("unroll") for (int r = 0; r < 2; ++r) {                           \
      int s = tid + r * 256; int row = s >> 4, c = s & 15;                    \
      *(int4*)(&thT[buf][row * 128 + ((c ^ (row & 7)) * 8)]) = rt[r]; } }
  LSUM_LOAD(0); LSUM_WRITE(0); __syncthreads();
  int cur = 0;
  const int swz = il & 7;
  for (int it = 0; it < NIT; ++it) {
    if (it + 1 < NIT) LSUM_LOAD(it + 1);
    f32x16 s16;
#pragma unroll
    for (int r = 0; r < 16; ++r) s16[r] = 0.f;
#pragma unroll
    for (int kk = 0; kk < 8; ++kk) {
      bf16x8 a = *(const bf16x8*)(&thT[cur][il * 128 + (((2 * kk + h) ^ swz) * 8)]);
      s16 = __builtin_amdgcn_mfma_f32_32x32x16_bf16(a, pf[kk], s16, 0, 0, 0);
    }
#pragma unroll
    for (int r = 0; r < 16; ++r) lsum += __expf(s16[r]);
    if (it + 1 < NIT) LSUM_WRITE(cur ^ 1);
    __syncthreads();
    cur ^= 1;
  }
  lsum += __shfl_xor(lsum, 32);
  if (h == 0)
    plsum[((size_t)(b * ISPLIT + iy) << 12) + j0 + w * 32 + il] = lsum;
#undef LSUM_LOAD
#undef LSUM_WRITE
}

// ---------------- attention, 32x32x16 MFMA (R19-verified) ----------------
__global__ __launch_bounds__(256, 2) void k_attn(
    const short* __restrict__ phiB, const short* __restrict__ thetaB,
    const short* __restrict__ gB, short* __restrict__ omidP) {
  __shared__ short phiT[2][32 * 128];   // 8KB each, chunk-swizzled ^(row&7)
  __shared__ short gT[2][256 * 32];     // 16KB each, slot-swizzled ^((row>>1)&3)
  __shared__ short pT[4][32 * 32];      // 2KB per wave, slot-swizzled
  const int tid = threadIdx.x, lane = tid & 63, w = tid >> 6;
  const int il = lane & 31, h = lane >> 5;
  const int key = (il >> 1) & 3;        // 16B-slot swizzle key (row = il)
  const int i0 = blockIdx.x * 128, jq = blockIdx.y, b = blockIdx.z;
  const short* phb = phiB + (size_t)b * NPOS * NCI;
  const short* thb = thetaB + (size_t)b * NPOS * NCI;
  const short* gb = gB + (size_t)b * NC * NPOS;
  short* om = omidP + ((size_t)(jq * NB + b)) * NC * NPOS;

  bf16x8 tf[8];
  {
    const short* tr = thb + (size_t)(i0 + w * 32 + il) * NCI;
#pragma unroll
    for (int kk = 0; kk < 8; ++kk) tf[kk] = *(const bf16x8*)(tr + kk * 16 + h * 8);
  }
  f32x16 acc[8];
#pragma unroll
  for (int i = 0; i < 8; ++i)
#pragma unroll
    for (int r = 0; r < 16; ++r) acc[i][r] = 0.f;

  int4 rphi[2], rg[4];
  const int NT = 32;                    // 32 j-tiles of 32 per quarter
  const int jbase = jq * 32;
#define ATTN_LOAD(jt)                                                          \
  { _Pragma("unroll") for (int r = 0; r < 2; ++r) {                            \
      int s = tid + r * 256; int row = s >> 4, c = s & 15;                     \
      rphi[r] = *(const int4*)(phb + (size_t)((jbase + (jt)) * 32 + row) * NCI + c * 8); } \
    _Pragma("unroll") for (int r = 0; r < 4; ++r) {                            \
      int s = tid + r * 256; int cc = s >> 2, c4 = s & 3;                      \
      rg[r] = *(const int4*)(gb + (size_t)cc * NPOS + (jbase + (jt)) * 32 + c4 * 8); } }
#define ATTN_WRITE(buf)                                                        \
  { _Pragma("unroll") for (int r = 0; r < 2; ++r) {                            \
      int s = tid + r * 256; int row = s >> 4, c = s & 15;                     \
      *(int4*)(&phiT[buf][row * 128 + ((c ^ (row & 7)) * 8)]) = rphi[r]; }     \
    _Pragma("unroll") for (int r = 0; r < 4; ++r) {                            \
      int s = tid + r * 256; int cc = s >> 2, c4 = s & 3;                      \
      *(int4*)(&gT[buf][cc * 32 + ((c4 ^ ((cc >> 1) & 3)) * 8)]) = rg[r]; } }
  ATTN_LOAD(0); ATTN_WRITE(0); __syncthreads();
  int cur = 0;
  for (int jt = 0; jt < NT; ++jt) {
    if (jt + 1 < NT) ATTN_LOAD(jt + 1);
    {
      const short* PH = &phiT[cur][0];
      short* PW = &pT[w][0];
      // ---- S^T: 32 j x 32 i, K=128 via 8 mfma 32x32x16 ----
      f32x16 s16;
#pragma unroll
      for (int r = 0; r < 16; ++r) s16[r] = 0.f;
      const int swp = il & 7;           // phi chunk swizzle (row = j = il)
#pragma unroll
      for (int kk = 0; kk < 8; ++kk) {
        bf16x8 a = *(const bf16x8*)(PH + il * 128 + (((2 * kk + h) ^ swp) * 8));
        s16 = __builtin_amdgcn_mfma_f32_32x32x16_bf16(a, tf[kk], s16, 0, 0, 0);
      }
      // lane holds S^T[j=(r&3)+8*(r>>2)+4h][i = i0+w*32+il]; P = exp(S)
#pragma unroll
      for (int g2 = 0; g2 < 4; ++g2) {
        unsigned short p0 = f2bf(__expf(s16[4 * g2 + 0]));
        unsigned short p1 = f2bf(__expf(s16[4 * g2 + 1]));
        unsigned short p2 = f2bf(__expf(s16[4 * g2 + 2]));
        unsigned short p3 = f2bf(__expf(s16[4 * g2 + 3]));
        unsigned int lo = (unsigned int)p0 | ((unsigned int)p1 << 16);
        unsigned int hi2 = (unsigned int)p2 | ((unsigned int)p3 << 16);
        *(uint2*)(PW + il * 32 + ((g2 ^ key) * 8) + 4 * h) = make_uint2(lo, hi2);
      }
      // ---- PV: wave's 32 i x all 256 cc ----
      const short* GT = &gT[cur][0];
      bf16x8 pa[2];
#pragma unroll
      for (int jh2 = 0; jh2 < 2; ++jh2)
        pa[jh2] = *(const bf16x8*)(PW + il * 32 + (((2 * jh2 + h) ^ key) * 8));
#pragma unroll
      for (int ct = 0; ct < 8; ++ct) {
#pragma unroll
        for (int jh2 = 0; jh2 < 2; ++jh2) {
          bf16x8 bg = *(const bf16x8*)(GT + (ct * 32 + il) * 32 + (((2 * jh2 + h) ^ key) * 8));
          acc[ct] = __builtin_amdgcn_mfma_f32_32x32x16_bf16(pa[jh2], bg, acc[ct], 0, 0, 0);
        }
      }
    }
    if (jt + 1 < NT) ATTN_WRITE(cur ^ 1);
    __syncthreads();
    cur ^= 1;
  }
#pragma unroll
  for (int ct = 0; ct < 8; ++ct)
#pragma unroll
    for (int g2 = 0; g2 < 4; ++g2) {
      __align__(8) short pv[4];
#pragma unroll
      for (int e = 0; e < 4; ++e) pv[e] = (short)f2bf(acc[ct][4 * g2 + e]);
      size_t o = (size_t)(ct * 32 + il) * NPOS + i0 + w * 32 + 8 * g2 + 4 * h;
      *(uint2*)(om + o) = *(const uint2*)pv;
    }
#undef ATTN_LOAD
#undef ATTN_WRITE
}

extern "C" void kernel_launch(void* const* d_in, const int* in_sizes, int n_in,
                              void* d_out, int out_size, void* d_ws, size_t ws_size,
                              hipStream_t stream) {
  (void)in_sizes; (void)n_in; (void)out_size; (void)ws_size;
  const float* x0      = (const float*)d_in[0];
  const float* x       = (const float*)d_in[1];
  const float* x_dsm   = (const float*)d_in[2];
  const float* w_phi   = (const float*)d_in[3];
  const float* w_theta = (const float*)d_in[4];
  const float* w_g     = (const float*)d_in[5];
  const float* w_mask  = (const float*)d_in[6];
  float* outp = (float*)d_out;

  short* sp = (short*)d_ws;
  short* wb_phi   = sp; sp += 32768;
  short* wb_theta = sp; sp += 32768;
  short* wb_g     = sp; sp += 131072;
  short* wb_mask  = sp; sp += 131072;
  short* xT   = sp; sp += (size_t)NB * NPOS * NC;          // 8MB
  short* xdT  = sp; sp += (size_t)NB * NPOS * NC;          // 8MB
  short* x0T  = sp; sp += (size_t)NB * NPOS * NC2;         // 16MB
  short* phiB   = sp; sp += (size_t)NB * NPOS * NCI;       // 4MB
  short* thetaB = sp; sp += (size_t)NB * NPOS * NCI;       // 4MB
  short* gBuf   = sp; sp += (size_t)NB * NC * NPOS;        // 8MB
  float* plsum = (float*)sp;                               // [b][ISPLIT][NPOS]
  short* omidP = xT;       // 4 bf16 partials x 8MB = 32MB, aliases dead xT/xdT/x0T
  short* omidT = phiB;     // 8MB bf16 [b][p][cc], aliases dead phiB/thetaB

  // transpose-casts + weight cast (y==16)
  k_tcast_all<<<dim3(64, 17, NB), 256, 0, stream>>>(
      x, x_dsm, x0, xT, xdT, x0T,
      w_phi, wb_phi, w_theta, wb_theta, w_g, wb_g, w_mask, wb_mask);

  // phi + theta in one dispatch (z<NB: phi from xT; z>=NB: theta from xdT)
  k_gemm<true, false, false, true><<<dim3(64, 2, 2 * NB), 256, 0, stream>>>(
      wb_phi, xT, phiB, nullptr, nullptr, wb_theta, xdT, thetaB,
      NC, NCI, 0, (size_t)NPOS * NC, (size_t)NPOS * NCI);

  k_lsum<<<dim3(NPOS / 128, ISPLIT, NB), 256, 0, stream>>>(phiB, thetaB, plsum);

  // g[cc][p] = (sum_c x0T[p][c] W_g[cc][c]) * (1/sum_t plsum[b][t][p])
  k_gemm<true, false, true, false><<<dim3(4, 64, NB), 256, 0, stream>>>(
      x0T, wb_g, gBuf, nullptr, plsum, nullptr, nullptr, nullptr,
      NC2, NPOS, (size_t)NPOS * NC2, 0, (size_t)NC * NPOS);

  k_attn<<<dim3(NPOS / 128, 4, NB), 256, 0, stream>>>(phiB, thetaB, gBuf, omidP);

  k_tcast4<<<dim3(64, 4, NB), 256, 0, stream>>>(omidP, omidT);

  k_gemm<false, true, false, false><<<dim3(8, 64, NB), 256, 0, stream>>>(
      omidT, wb_mask, outp, x0, nullptr, nullptr, nullptr, nullptr,
      NC, NPOS, (size_t)NPOS * NC, 0, (size_t)NC2 * NPOS);
}